// Round 1
// baseline (903.785 us; speedup 1.0000x reference)
//
#include <hip/hip_runtime.h>

typedef _Float16 f16;
typedef unsigned short u16;
typedef unsigned int u32;
typedef f16 f16x8 __attribute__((ext_vector_type(8)));
typedef f16 f16x4 __attribute__((ext_vector_type(4)));
typedef float f32x4 __attribute__((ext_vector_type(4)));

// Problem constants: N=4,T=8,H=64,W=64,C=512, WS=8, heads=8, head_dim=64
// windows = 32*8*8 = 2048, tokens/window = 64, M = 131072, K = 512, Nqkv = 1536

// window-major row m -> row index in x viewed as (32*64*64, 512)
__device__ __forceinline__ int src_row(int m) {
    int win = m >> 6, s = m & 63;
    return ((win >> 6) << 12) | (((win >> 3) & 7) << 9) | ((s >> 3) << 6) |
           ((win & 7) << 3) | (s & 7);
}

__device__ __forceinline__ void gload_lds16(const void* g, void* lds) {
    __builtin_amdgcn_global_load_lds(
        (const __attribute__((address_space(1))) u32*)g,
        (__attribute__((address_space(3))) u32*)lds, 16, 0, 0);
}

// ---------------- prep: weights fp32 -> fp16 ----------------
__global__ __launch_bounds__(256) void prep_weights_k(
        const float* __restrict__ Wi, const float* __restrict__ Wo,
        f16* __restrict__ Wi_h, f16* __restrict__ Wo_h) {
    int i = blockIdx.x * 256 + threadIdx.x;    // 262144 float4s total
    const float4* src;
    f16* dst;
    int idx;
    if (i < 196608) { src = (const float4*)Wi; dst = Wi_h; idx = i; }
    else            { src = (const float4*)Wo; dst = Wo_h; idx = i - 196608; }
    float4 v = src[idx];
    f16x4 h = {(f16)v.x, (f16)v.y, (f16)v.z, (f16)v.w};
    *(f16x4*)(dst + (size_t)idx * 4) = h;
}

// ---------------- prep: bias table biasT[s][o] = b_in[o] + (o<1024 ? pos[s]·W_in[o] : 0)
__global__ __launch_bounds__(256) void prep_bias_k(
        const float* __restrict__ pos, const float* __restrict__ Wi,
        const float* __restrict__ b_in, float* __restrict__ biasT) {
    int idx = blockIdx.x * 256 + threadIdx.x;   // 64*1536 = 98304
    int s = idx / 1536, o = idx % 1536;
    float acc = b_in[o];
    if (o < 1024) {
        const float4* p4 = (const float4*)(pos + (size_t)s * 512);
        const float4* w4 = (const float4*)(Wi + (size_t)o * 512);
        #pragma unroll 4
        for (int c = 0; c < 128; ++c) {
            float4 a = p4[c], b = w4[c];
            acc += a.x * b.x + a.y * b.y + a.z * b.z + a.w * b.w;
        }
    }
    biasT[idx] = acc;
}

// ---------------- QKV GEMM: qkv[m][o] = f16( x_perm[m]·W_in[o] + biasT[m&63][o] )
// 128x128 tile, BK=32, 4 waves (2x2 of 64x64), A reg-staged fp32->f16, B via global_load_lds
__global__ __launch_bounds__(256) void qkv_gemm_k(
        const float* __restrict__ x, const f16* __restrict__ Wh,
        const float* __restrict__ biasT, f16* __restrict__ qkv, int m0) {
    __shared__ f16 As[128 * 32];
    __shared__ f16 Bs[128 * 32];
    int tid = threadIdx.x;
    int lane = tid & 63, wid = tid >> 6;
    int l15 = lane & 15, g = lane >> 4;
    int bn = blockIdx.x % 12, bm = blockIdx.x / 12;
    int brow = bm * 128, bcol = bn * 128;
    int wm = wid >> 1, wn = wid & 1;

    // A staging map: 4 passes of 32 rows; 8 threads/row, float4 each
    int ar = tid >> 3, aq = tid & 7;
    int soff[4];
    #pragma unroll
    for (int p = 0; p < 4; ++p) {
        int m = m0 + brow + p * 32 + ar;
        soff[p] = src_row(m) * 512 + aq * 4;
    }
    // B staging map (per 1KB chunk): lane -> row = chunk*16 + (lane>>2), col = (lane&3)*8
    int brB = lane >> 2, bcB = (lane & 3) * 8;

    f32x4 zero4 = {0.f, 0.f, 0.f, 0.f};
    f32x4 acc[4][4];
    #pragma unroll
    for (int a = 0; a < 4; ++a)
        #pragma unroll
        for (int b = 0; b < 4; ++b) acc[a][b] = zero4;

    for (int kt = 0; kt < 16; ++kt) {
        int k0 = kt * 32;
        #pragma unroll
        for (int i = 0; i < 2; ++i) {
            int chunk = wid * 2 + i;
            gload_lds16(Wh + (size_t)(bcol + chunk * 16 + brB) * 512 + k0 + bcB,
                        (void*)&Bs[chunk * 512]);
        }
        #pragma unroll
        for (int p = 0; p < 4; ++p) {
            float4 v = *(const float4*)(x + soff[p] + k0);
            f16x4 h = {(f16)v.x, (f16)v.y, (f16)v.z, (f16)v.w};
            *(f16x4*)&As[(p * 32 + ar) * 32 + aq * 4] = h;
        }
        __syncthreads();
        f16x8 af[4], bfr[4];
        #pragma unroll
        for (int mf = 0; mf < 4; ++mf)
            af[mf] = *reinterpret_cast<const f16x8*>(&As[(wm * 64 + mf * 16 + l15) * 32 + g * 8]);
        #pragma unroll
        for (int nf = 0; nf < 4; ++nf)
            bfr[nf] = *reinterpret_cast<const f16x8*>(&Bs[(wn * 64 + nf * 16 + l15) * 32 + g * 8]);
        #pragma unroll
        for (int mf = 0; mf < 4; ++mf)
            #pragma unroll
            for (int nf = 0; nf < 4; ++nf)
                acc[mf][nf] = __builtin_amdgcn_mfma_f32_16x16x32_f16(af[mf], bfr[nf], acc[mf][nf], 0, 0, 0);
        __syncthreads();
    }

    #pragma unroll
    for (int mf = 0; mf < 4; ++mf) {
        #pragma unroll
        for (int nf = 0; nf < 4; ++nf) {
            int col = bcol + wn * 64 + nf * 16 + l15;
            #pragma unroll
            for (int j = 0; j < 4; ++j) {
                int rowl = brow + wm * 64 + mf * 16 + g * 4 + j;
                float v = acc[mf][nf][j] + biasT[(rowl & 63) * 1536 + col];
                qkv[(size_t)rowl * 1536 + col] = (f16)v;
            }
        }
    }
}

// ---------------- attention: one wave per (window, head); 64x64 flash block
__global__ __launch_bounds__(256) void attn_k(
        const f16* __restrict__ qkv, f16* __restrict__ attn_out) {
    __shared__ f16 P[4][64 * 64];
    int tid = threadIdx.x;
    int lane = tid & 63, wid = tid >> 6;
    int l15 = lane & 15, g = lane >> 4;
    int winl = blockIdx.x >> 1;
    int head = (blockIdx.x & 1) * 4 + wid;
    const f16* base = qkv + (size_t)winl * 64 * 1536;
    int qc = head * 64, kc = 512 + head * 64, vc = 1024 + head * 64;

    f32x4 zero4 = {0.f, 0.f, 0.f, 0.f};
    f32x4 acc[4][4];
    #pragma unroll
    for (int a = 0; a < 4; ++a)
        #pragma unroll
        for (int b = 0; b < 4; ++b) acc[a][b] = zero4;

    {   // scores = q @ k^T
        f16x8 qf[4][2], kf[4][2];
        #pragma unroll
        for (int mf = 0; mf < 4; ++mf)
            #pragma unroll
            for (int ks = 0; ks < 2; ++ks)
                qf[mf][ks] = *reinterpret_cast<const f16x8*>(base + (size_t)(mf * 16 + l15) * 1536 + qc + ks * 32 + g * 8);
        #pragma unroll
        for (int nf = 0; nf < 4; ++nf)
            #pragma unroll
            for (int ks = 0; ks < 2; ++ks)
                kf[nf][ks] = *reinterpret_cast<const f16x8*>(base + (size_t)(nf * 16 + l15) * 1536 + kc + ks * 32 + g * 8);
        #pragma unroll
        for (int ks = 0; ks < 2; ++ks)
            #pragma unroll
            for (int mf = 0; mf < 4; ++mf)
                #pragma unroll
                for (int nf = 0; nf < 4; ++nf)
                    acc[mf][nf] = __builtin_amdgcn_mfma_f32_16x16x32_f16(qf[mf][ks], kf[nf][ks], acc[mf][nf], 0, 0, 0);
    }

    // V fragments (B-operand: lane&15 = d, 8 s-values per lane -> strided scalar loads, L1-hot)
    f16x8 vf[4][2];
    #pragma unroll
    for (int nf = 0; nf < 4; ++nf)
        #pragma unroll
        for (int ks = 0; ks < 2; ++ks) {
            f16x8 v;
            #pragma unroll
            for (int j = 0; j < 8; ++j)
                v[j] = base[(size_t)(ks * 32 + g * 8 + j) * 1536 + vc + nf * 16 + l15];
            vf[nf][ks] = v;
        }

    // softmax over keys (row r = mf*16 + g*4 + j lives in 16-lane group g across 4 nf frags)
    #pragma unroll
    for (int mf = 0; mf < 4; ++mf) {
        #pragma unroll
        for (int j = 0; j < 4; ++j) {
            float mx = -1e30f;
            #pragma unroll
            for (int nf = 0; nf < 4; ++nf) mx = fmaxf(mx, acc[mf][nf][j]);
            #pragma unroll
            for (int off = 1; off < 16; off <<= 1) mx = fmaxf(mx, __shfl_xor(mx, off));
            float e[4], sum = 0.f;
            #pragma unroll
            for (int nf = 0; nf < 4; ++nf) {
                e[nf] = __expf((acc[mf][nf][j] - mx) * 0.125f);
                sum += e[nf];
            }
            #pragma unroll
            for (int off = 1; off < 16; off <<= 1) sum += __shfl_xor(sum, off);
            float rinv = __fdividef(1.0f, sum);
            int row = mf * 16 + g * 4 + j;
            #pragma unroll
            for (int nf = 0; nf < 4; ++nf)
                P[wid][row * 64 + nf * 16 + l15] = (f16)(e[nf] * rinv);
        }
    }
    __syncthreads();

    // out = P @ V  (reuse acc)
    #pragma unroll
    for (int a = 0; a < 4; ++a)
        #pragma unroll
        for (int b = 0; b < 4; ++b) acc[a][b] = zero4;
    #pragma unroll
    for (int ks = 0; ks < 2; ++ks)
        #pragma unroll
        for (int mf = 0; mf < 4; ++mf) {
            f16x8 pa = *reinterpret_cast<const f16x8*>(&P[wid][(mf * 16 + l15) * 64 + ks * 32 + g * 8]);
            #pragma unroll
            for (int nf = 0; nf < 4; ++nf)
                acc[mf][nf] = __builtin_amdgcn_mfma_f32_16x16x32_f16(pa, vf[nf][ks], acc[mf][nf], 0, 0, 0);
        }
    #pragma unroll
    for (int mf = 0; mf < 4; ++mf)
        #pragma unroll
        for (int nf = 0; nf < 4; ++nf)
            #pragma unroll
            for (int j = 0; j < 4; ++j)
                attn_out[(size_t)(winl * 64 + mf * 16 + g * 4 + j) * 512 + head * 64 + nf * 16 + l15] =
                    (f16)acc[mf][nf][j];
}

// ---------------- output GEMM + scatter: out[src_row(m)][o] = attn[m]·W_out[o] + b_out[o]
__global__ __launch_bounds__(256) void out_gemm_k(
        const f16* __restrict__ attn, const f16* __restrict__ Woh,
        const float* __restrict__ b_out, float* __restrict__ out, int m0) {
    __shared__ f16 As[128 * 32];
    __shared__ f16 Bs[128 * 32];
    int tid = threadIdx.x;
    int lane = tid & 63, wid = tid >> 6;
    int l15 = lane & 15, g = lane >> 4;
    int bn = blockIdx.x & 3, bm = blockIdx.x >> 2;
    int brow = bm * 128, bcol = bn * 128;
    int wm = wid >> 1, wn = wid & 1;
    int brB = lane >> 2, bcB = (lane & 3) * 8;

    f32x4 zero4 = {0.f, 0.f, 0.f, 0.f};
    f32x4 acc[4][4];
    #pragma unroll
    for (int a = 0; a < 4; ++a)
        #pragma unroll
        for (int b = 0; b < 4; ++b) acc[a][b] = zero4;

    for (int kt = 0; kt < 16; ++kt) {
        int k0 = kt * 32;
        #pragma unroll
        for (int i = 0; i < 2; ++i) {
            int chunk = wid * 2 + i;
            gload_lds16(attn + (size_t)(brow + chunk * 16 + brB) * 512 + k0 + bcB,
                        (void*)&As[chunk * 512]);
            gload_lds16(Woh + (size_t)(bcol + chunk * 16 + brB) * 512 + k0 + bcB,
                        (void*)&Bs[chunk * 512]);
        }
        __syncthreads();
        f16x8 af[4], bfr[4];
        #pragma unroll
        for (int mf = 0; mf < 4; ++mf)
            af[mf] = *reinterpret_cast<const f16x8*>(&As[(wm * 64 + mf * 16 + l15) * 32 + g * 8]);
        #pragma unroll
        for (int nf = 0; nf < 4; ++nf)
            bfr[nf] = *reinterpret_cast<const f16x8*>(&Bs[(wn * 64 + nf * 16 + l15) * 32 + g * 8]);
        #pragma unroll
        for (int mf = 0; mf < 4; ++mf)
            #pragma unroll
            for (int nf = 0; nf < 4; ++nf)
                acc[mf][nf] = __builtin_amdgcn_mfma_f32_16x16x32_f16(af[mf], bfr[nf], acc[mf][nf], 0, 0, 0);
        __syncthreads();
    }

    #pragma unroll
    for (int mf = 0; mf < 4; ++mf) {
        #pragma unroll
        for (int nf = 0; nf < 4; ++nf) {
            int col = bcol + wn * 64 + nf * 16 + l15;
            float bo = b_out[col];
            #pragma unroll
            for (int j = 0; j < 4; ++j) {
                int ml = brow + wm * 64 + mf * 16 + g * 4 + j;
                int srow = src_row(m0 + ml);
                out[(size_t)srow * 512 + col] = acc[mf][nf][j] + bo;
            }
        }
    }
}

extern "C" void kernel_launch(void* const* d_in, const int* in_sizes, int n_in,
                              void* d_out, int out_size, void* d_ws, size_t ws_size,
                              hipStream_t stream) {
    (void)in_sizes; (void)n_in; (void)out_size;
    const float* x     = (const float*)d_in[0];
    const float* pos   = (const float*)d_in[1];
    const float* W_in  = (const float*)d_in[2];
    const float* b_in  = (const float*)d_in[3];
    const float* W_out = (const float*)d_in[4];
    const float* b_out = (const float*)d_in[5];
    float* out = (float*)d_out;

    char* ws = (char*)d_ws;
    f16*   Wi_h  = (f16*)ws;                  // 1536*512*2 = 1,572,864 B
    f16*   Wo_h  = (f16*)(ws + 1572864);      //  512*512*2 =   524,288 B
    float* biasT = (float*)(ws + 2097152);    //  64*1536*4 =   393,216 B
    const size_t fixed = 2490368;

    // adaptive chunking of the 2048 windows so scratch fits ws_size
    int chunks = 1;
    while (chunks < 64) {
        size_t need = fixed + ((size_t)131072 / chunks) * 2048 * 2;  // qkv + attn rows (f16)
        if (need <= ws_size) break;
        chunks <<= 1;
    }
    int Mc = 131072 / chunks;
    f16* qkv  = (f16*)(ws + fixed);
    f16* attn = (f16*)(ws + fixed + (size_t)Mc * 1536 * 2);

    prep_weights_k<<<1024, 256, 0, stream>>>(W_in, W_out, Wi_h, Wo_h);
    prep_bias_k<<<384, 256, 0, stream>>>(pos, W_in, b_in, biasT);
    for (int c = 0; c < chunks; ++c) {
        int m0 = c * Mc;
        qkv_gemm_k<<<(Mc / 128) * 12, 256, 0, stream>>>(x, Wi_h, biasT, qkv, m0);
        attn_k<<<(Mc / 64) * 2, 256, 0, stream>>>(qkv, attn);
        out_gemm_k<<<(Mc / 128) * 4, 256, 0, stream>>>(attn, Wo_h, b_out, out, m0);
    }
}

// Round 2
// 707.622 us; speedup vs baseline: 1.2772x; 1.2772x over previous
//
#include <hip/hip_runtime.h>

typedef _Float16 f16;
typedef unsigned int u32;
typedef f16 f16x8 __attribute__((ext_vector_type(8)));
typedef f16 f16x4 __attribute__((ext_vector_type(4)));
typedef float f32x4 __attribute__((ext_vector_type(4)));

// N=4,T=8,H=64,W=64,C=512, WS=8, heads=8, head_dim=64
// windows = 2048, tokens/window = 64, M = 131072, K = 512, Nqkv = 1536

__device__ __forceinline__ int src_row(int m) {
    int win = m >> 6, s = m & 63;
    return ((win >> 6) << 12) | (((win >> 3) & 7) << 9) | ((s >> 3) << 6) |
           ((win & 7) << 3) | (s & 7);
}

__device__ __forceinline__ void gload_lds16(const void* g, void* lds) {
    __builtin_amdgcn_global_load_lds(
        (const __attribute__((address_space(1))) u32*)g,
        (__attribute__((address_space(3))) u32*)lds, 16, 0, 0);
}

// swizzled LDS accessor: 64 rows x 512 f16, row stride 1024 B, XOR bits 4-6
__device__ __forceinline__ f16* sp(char* S, int r, int c) {
    return (f16*)(S + r * 1024 + ((c * 2) ^ ((r & 7) << 4)));
}

// ---------------- prep: weights fp32 -> fp16 ----------------
__global__ __launch_bounds__(256) void prep_weights_k(
        const float* __restrict__ Wi, const float* __restrict__ Wo,
        f16* __restrict__ Wi_h, f16* __restrict__ Wo_h) {
    int i = blockIdx.x * 256 + threadIdx.x;    // 262144 float4s total
    const float4* src;
    f16* dst;
    int idx;
    if (i < 196608) { src = (const float4*)Wi; dst = Wi_h; idx = i; }
    else            { src = (const float4*)Wo; dst = Wo_h; idx = i - 196608; }
    float4 v = src[idx];
    f16x4 h = {(f16)v.x, (f16)v.y, (f16)v.z, (f16)v.w};
    *(f16x4*)(dst + (size_t)idx * 4) = h;
}

// ---------------- prep: biasT[s][o] = b_in[o] + (o<1024 ? pos[s]·W_in[o] : 0)
__global__ __launch_bounds__(256) void prep_bias_k(
        const float* __restrict__ pos, const float* __restrict__ Wi,
        const float* __restrict__ b_in, float* __restrict__ biasT) {
    int idx = blockIdx.x * 256 + threadIdx.x;   // 64*1536
    int s = idx / 1536, o = idx % 1536;
    float acc = b_in[o];
    if (o < 1024) {
        const float4* p4 = (const float4*)(pos + (size_t)s * 512);
        const float4* w4 = (const float4*)(Wi + (size_t)o * 512);
        #pragma unroll 4
        for (int c = 0; c < 128; ++c) {
            float4 a = p4[c], b = w4[c];
            acc += a.x * b.x + a.y * b.y + a.z * b.z + a.w * b.w;
        }
    }
    biasT[idx] = acc;
}

// ---------------- prep: x fp32 -> window-major f16 chunk ----------------
__global__ __launch_bounds__(256) void prep_x_k(
        const float* __restrict__ x, f16* __restrict__ xh, int m0) {
    int i = blockIdx.x * 256 + threadIdx.x;    // Mc*64
    int ml = i >> 6, c8 = (i & 63) * 8;
    int sr = src_row(m0 + ml);
    const float4* s4 = (const float4*)(x + (size_t)sr * 512 + c8);
    float4 a = s4[0], b = s4[1];
    f16x8 hv = {(f16)a.x, (f16)a.y, (f16)a.z, (f16)a.w,
                (f16)b.x, (f16)b.y, (f16)b.z, (f16)b.w};
    *(f16x8*)(xh + (size_t)ml * 512 + c8) = hv;
}

// ---------------- QKV GEMM (m97 structure): qkv[m][o] = f16(xh[m]·W_in[o] + biasT[m&63][o])
__global__ __launch_bounds__(256) void qkv_gemm_k(
        const f16* __restrict__ xh, const f16* __restrict__ Wh,
        const float* __restrict__ biasT, f16* __restrict__ qkv, int nblk) {
    __shared__ f16 As[128 * 32];
    __shared__ f16 Bs[128 * 32];
    int tid = threadIdx.x;
    int lane = tid & 63, wid = tid >> 6;
    int l15 = lane & 15, g = lane >> 4;
    // XCD-aware bijective swizzle (nblk % 8 == 0)
    int sid = (blockIdx.x & 7) * (nblk >> 3) + (blockIdx.x >> 3);
    int bn = sid % 12, bm = sid / 12;
    int brow = bm * 128, bcol = bn * 128;
    int wm = wid >> 1, wn = wid & 1;
    int brB = lane >> 2, bcB = (lane & 3) * 8;

    const f16* Abase = xh + (size_t)brow * 512;
    const f16* Bbase = Wh + (size_t)bcol * 512;

    f32x4 zero4 = {0.f, 0.f, 0.f, 0.f};
    f32x4 acc[4][4];
    #pragma unroll
    for (int a = 0; a < 4; ++a)
        #pragma unroll
        for (int b = 0; b < 4; ++b) acc[a][b] = zero4;

    for (int kt = 0; kt < 16; ++kt) {
        int k0 = kt * 32;
        #pragma unroll
        for (int i = 0; i < 2; ++i) {
            int chunk = wid * 2 + i;
            gload_lds16(Abase + (size_t)(chunk * 16 + brB) * 512 + k0 + bcB,
                        (void*)&As[chunk * 512]);
            gload_lds16(Bbase + (size_t)(chunk * 16 + brB) * 512 + k0 + bcB,
                        (void*)&Bs[chunk * 512]);
        }
        __syncthreads();
        f16x8 af[4], bfr[4];
        #pragma unroll
        for (int mf = 0; mf < 4; ++mf)
            af[mf] = *reinterpret_cast<const f16x8*>(&As[(wm * 64 + mf * 16 + l15) * 32 + g * 8]);
        #pragma unroll
        for (int nf = 0; nf < 4; ++nf)
            bfr[nf] = *reinterpret_cast<const f16x8*>(&Bs[(wn * 64 + nf * 16 + l15) * 32 + g * 8]);
        #pragma unroll
        for (int mf = 0; mf < 4; ++mf)
            #pragma unroll
            for (int nf = 0; nf < 4; ++nf)
                acc[mf][nf] = __builtin_amdgcn_mfma_f32_16x16x32_f16(af[mf], bfr[nf], acc[mf][nf], 0, 0, 0);
        __syncthreads();
    }

    #pragma unroll
    for (int mf = 0; mf < 4; ++mf) {
        #pragma unroll
        for (int nf = 0; nf < 4; ++nf) {
            int col = bcol + wn * 64 + nf * 16 + l15;
            #pragma unroll
            for (int j = 0; j < 4; ++j) {
                int rowl = brow + wm * 64 + mf * 16 + g * 4 + j;
                float v = acc[mf][nf][j] + biasT[(rowl & 63) * 1536 + col];
                qkv[(size_t)rowl * 1536 + col] = (f16)v;
            }
        }
    }
}

// ---------------- fused attention + output projection ----------------
// one block per window: 8 waves = 8 heads; swizzled 64x512 f16 LDS holds P then attn-out
__global__ __launch_bounds__(512) void attn_out_k(
        const f16* __restrict__ qkv, const f16* __restrict__ Woh,
        const float* __restrict__ b_out, float* __restrict__ out, int w0) {
    __shared__ __align__(16) char S[64 * 1024];
    int tid = threadIdx.x;
    int lane = tid & 63, h = tid >> 6;   // wave = head
    int l15 = lane & 15, g = lane >> 4;
    const f16* base = qkv + (size_t)blockIdx.x * 64 * 1536;
    int qc = h * 64, kc = 512 + h * 64, vc = 1024 + h * 64;

    f32x4 zero4 = {0.f, 0.f, 0.f, 0.f};
    f32x4 acc[4][4];
    #pragma unroll
    for (int a = 0; a < 4; ++a)
        #pragma unroll
        for (int b = 0; b < 4; ++b) acc[a][b] = zero4;

    {   // scores = q @ k^T
        f16x8 qf[4][2], kf[4][2];
        #pragma unroll
        for (int mf = 0; mf < 4; ++mf)
            #pragma unroll
            for (int ks = 0; ks < 2; ++ks)
                qf[mf][ks] = *reinterpret_cast<const f16x8*>(base + (size_t)(mf * 16 + l15) * 1536 + qc + ks * 32 + g * 8);
        #pragma unroll
        for (int nf = 0; nf < 4; ++nf)
            #pragma unroll
            for (int ks = 0; ks < 2; ++ks)
                kf[nf][ks] = *reinterpret_cast<const f16x8*>(base + (size_t)(nf * 16 + l15) * 1536 + kc + ks * 32 + g * 8);
        #pragma unroll
        for (int ks = 0; ks < 2; ++ks)
            #pragma unroll
            for (int mf = 0; mf < 4; ++mf)
                #pragma unroll
                for (int nf = 0; nf < 4; ++nf)
                    acc[mf][nf] = __builtin_amdgcn_mfma_f32_16x16x32_f16(qf[mf][ks], kf[nf][ks], acc[mf][nf], 0, 0, 0);
    }

    // V fragments (B-operand): strided f16 gathers, L2/L3-hot
    f16x8 vf[4][2];
    #pragma unroll
    for (int nf = 0; nf < 4; ++nf)
        #pragma unroll
        for (int ks = 0; ks < 2; ++ks) {
            f16x8 v;
            #pragma unroll
            for (int j = 0; j < 8; ++j)
                v[j] = base[(size_t)(ks * 32 + g * 8 + j) * 1536 + vc + nf * 16 + l15];
            vf[nf][ks] = v;
        }

    // softmax over keys; P -> swizzled LDS at cols [h*64, h*64+64)
    #pragma unroll
    for (int mf = 0; mf < 4; ++mf) {
        #pragma unroll
        for (int j = 0; j < 4; ++j) {
            float mx = -1e30f;
            #pragma unroll
            for (int nf = 0; nf < 4; ++nf) mx = fmaxf(mx, acc[mf][nf][j]);
            #pragma unroll
            for (int off = 1; off < 16; off <<= 1) mx = fmaxf(mx, __shfl_xor(mx, off));
            float e[4], sum = 0.f;
            #pragma unroll
            for (int nf = 0; nf < 4; ++nf) {
                e[nf] = __expf((acc[mf][nf][j] - mx) * 0.125f);
                sum += e[nf];
            }
            #pragma unroll
            for (int off = 1; off < 16; off <<= 1) sum += __shfl_xor(sum, off);
            float rinv = __fdividef(1.0f, sum);
            int row = mf * 16 + g * 4 + j;
            #pragma unroll
            for (int nf = 0; nf < 4; ++nf)
                *sp(S, row, h * 64 + nf * 16 + l15) = (f16)(e[nf] * rinv);
        }
    }

    // out_h = P @ V  (P from this wave's own LDS slice; no barrier needed)
    f32x4 acc2[4][4];
    #pragma unroll
    for (int a = 0; a < 4; ++a)
        #pragma unroll
        for (int b = 0; b < 4; ++b) acc2[a][b] = zero4;
    #pragma unroll
    for (int ks = 0; ks < 2; ++ks)
        #pragma unroll
        for (int mf = 0; mf < 4; ++mf) {
            f16x8 pa = *reinterpret_cast<const f16x8*>(sp(S, mf * 16 + l15, h * 64 + ks * 32 + g * 8));
            #pragma unroll
            for (int nf = 0; nf < 4; ++nf)
                acc2[mf][nf] = __builtin_amdgcn_mfma_f32_16x16x32_f16(pa, vf[nf][ks], acc2[mf][nf], 0, 0, 0);
        }
    // overwrite this head's P slice with its attention output (f16)
    #pragma unroll
    for (int mf = 0; mf < 4; ++mf)
        #pragma unroll
        for (int nf = 0; nf < 4; ++nf)
            #pragma unroll
            for (int j = 0; j < 4; ++j)
                *sp(S, mf * 16 + g * 4 + j, h * 64 + nf * 16 + l15) = (f16)acc2[mf][nf][j];

    __syncthreads();

    // output projection: wave h computes cols [h*64, h*64+64), K = 512 from LDS
    int ocol0 = h * 64;
    float bo[4];
    #pragma unroll
    for (int nf = 0; nf < 4; ++nf) bo[nf] = b_out[ocol0 + nf * 16 + l15];

    #pragma unroll
    for (int a = 0; a < 4; ++a)
        #pragma unroll
        for (int b = 0; b < 4; ++b) acc[a][b] = zero4;
    for (int ks = 0; ks < 16; ++ks) {
        f16x8 af[4], bf[4];
        #pragma unroll
        for (int mf = 0; mf < 4; ++mf)
            af[mf] = *reinterpret_cast<const f16x8*>(sp(S, mf * 16 + l15, ks * 32 + g * 8));
        #pragma unroll
        for (int nf = 0; nf < 4; ++nf)
            bf[nf] = *reinterpret_cast<const f16x8*>(Woh + (size_t)(ocol0 + nf * 16 + l15) * 512 + ks * 32 + g * 8);
        #pragma unroll
        for (int mf = 0; mf < 4; ++mf)
            #pragma unroll
            for (int nf = 0; nf < 4; ++nf)
                acc[mf][nf] = __builtin_amdgcn_mfma_f32_16x16x32_f16(af[mf], bf[nf], acc[mf][nf], 0, 0, 0);
    }

    int wglob = w0 + blockIdx.x;
    #pragma unroll
    for (int mf = 0; mf < 4; ++mf) {
        #pragma unroll
        for (int j = 0; j < 4; ++j) {
            int srow = src_row(wglob * 64 + mf * 16 + g * 4 + j);
            #pragma unroll
            for (int nf = 0; nf < 4; ++nf)
                out[(size_t)srow * 512 + ocol0 + nf * 16 + l15] = acc[mf][nf][j] + bo[nf];
        }
    }
}

extern "C" void kernel_launch(void* const* d_in, const int* in_sizes, int n_in,
                              void* d_out, int out_size, void* d_ws, size_t ws_size,
                              hipStream_t stream) {
    (void)in_sizes; (void)n_in; (void)out_size;
    const float* x     = (const float*)d_in[0];
    const float* pos   = (const float*)d_in[1];
    const float* W_in  = (const float*)d_in[2];
    const float* b_in  = (const float*)d_in[3];
    const float* W_out = (const float*)d_in[4];
    const float* b_out = (const float*)d_in[5];
    float* out = (float*)d_out;

    char* ws = (char*)d_ws;
    f16*   Wi_h  = (f16*)ws;                  // 1,572,864 B
    f16*   Wo_h  = (f16*)(ws + 1572864);      //   524,288 B
    float* biasT = (float*)(ws + 2097152);    //   393,216 B
    const size_t fixed = 2490368;

    // chunk so xh+qkv stay L3-resident AND fit ws (4096 B per row, same as R1 footprint)
    int chunks = 4;
    while (chunks < 64) {
        size_t need = fixed + ((size_t)131072 / chunks) * 4096;
        if (need <= ws_size) break;
        chunks <<= 1;
    }
    int Mc = 131072 / chunks;
    f16* xh  = (f16*)(ws + fixed);
    f16* qkv = (f16*)(ws + fixed + (size_t)Mc * 1024);
    int nblk = (Mc / 128) * 12;

    prep_weights_k<<<1024, 256, 0, stream>>>(W_in, W_out, Wi_h, Wo_h);
    prep_bias_k<<<384, 256, 0, stream>>>(pos, W_in, b_in, biasT);
    for (int c = 0; c < chunks; ++c) {
        int m0 = c * Mc;
        prep_x_k<<<Mc / 4, 256, 0, stream>>>(x, xh, m0);
        qkv_gemm_k<<<nblk, 256, 0, stream>>>(xh, Wi_h, biasT, qkv, nblk);
        attn_out_k<<<Mc / 64, 512, 0, stream>>>(qkv, Wo_h, b_out, out, c * (Mc / 64));
    }
}

// Round 3
// 650.025 us; speedup vs baseline: 1.3904x; 1.0886x over previous
//
#include <hip/hip_runtime.h>

typedef _Float16 f16;
typedef unsigned int u32;
typedef f16 f16x8 __attribute__((ext_vector_type(8)));
typedef f16 f16x4 __attribute__((ext_vector_type(4)));
typedef float f32x4 __attribute__((ext_vector_type(4)));

// N=4,T=8,H=64,W=64,C=512, WS=8, heads=8, head_dim=64
// windows = 2048, tokens/window = 64, M = 131072, K = 512, Nqkv = 1536

__device__ __forceinline__ int src_row(int m) {
    int win = m >> 6, s = m & 63;
    return ((win >> 6) << 12) | (((win >> 3) & 7) << 9) | ((s >> 3) << 6) |
           ((win & 7) << 3) | (s & 7);
}

__device__ __forceinline__ void gload_lds16(const void* g, void* lds) {
    __builtin_amdgcn_global_load_lds(
        (const __attribute__((address_space(1))) u32*)g,
        (__attribute__((address_space(3))) u32*)lds, 16, 0, 0);
}

// swizzled LDS accessor for attn kernel: 64 rows x 512 f16, XOR bits 4-6
__device__ __forceinline__ f16* sp(char* S, int r, int c) {
    return (f16*)(S + r * 1024 + ((c * 2) ^ ((r & 7) << 4)));
}

// ---------------- prep: weights fp32 -> fp16 ----------------
__global__ __launch_bounds__(256) void prep_weights_k(
        const float* __restrict__ Wi, const float* __restrict__ Wo,
        f16* __restrict__ Wi_h, f16* __restrict__ Wo_h) {
    int i = blockIdx.x * 256 + threadIdx.x;    // 262144 float4s total
    const float4* src;
    f16* dst;
    int idx;
    if (i < 196608) { src = (const float4*)Wi; dst = Wi_h; idx = i; }
    else            { src = (const float4*)Wo; dst = Wo_h; idx = i - 196608; }
    float4 v = src[idx];
    f16x4 h = {(f16)v.x, (f16)v.y, (f16)v.z, (f16)v.w};
    *(f16x4*)(dst + (size_t)idx * 4) = h;
}

// ---------------- prep: biasT[s][o] = b_in[o] + (o<1024 ? pos[s]·W_in[o] : 0)
__global__ __launch_bounds__(256) void prep_bias_k(
        const float* __restrict__ pos, const float* __restrict__ Wi,
        const float* __restrict__ b_in, float* __restrict__ biasT) {
    int idx = blockIdx.x * 256 + threadIdx.x;   // 64*1536
    int s = idx / 1536, o = idx % 1536;
    float acc = b_in[o];
    if (o < 1024) {
        const float4* p4 = (const float4*)(pos + (size_t)s * 512);
        const float4* w4 = (const float4*)(Wi + (size_t)o * 512);
        #pragma unroll 4
        for (int c = 0; c < 128; ++c) {
            float4 a = p4[c], b = w4[c];
            acc += a.x * b.x + a.y * b.y + a.z * b.z + a.w * b.w;
        }
    }
    biasT[idx] = acc;
}

// ---------------- prep: x fp32 -> window-major f16 chunk ----------------
__global__ __launch_bounds__(256) void prep_x_k(
        const float* __restrict__ x, f16* __restrict__ xh, int m0) {
    int i = blockIdx.x * 256 + threadIdx.x;    // Mc*64
    int ml = i >> 6, c8 = (i & 63) * 8;
    int sr = src_row(m0 + ml);
    const float4* s4 = (const float4*)(x + (size_t)sr * 512 + c8);
    float4 a = s4[0], b = s4[1];
    f16x8 hv = {(f16)a.x, (f16)a.y, (f16)a.z, (f16)a.w,
                (f16)b.x, (f16)b.y, (f16)b.z, (f16)b.w};
    *(f16x8*)(xh + (size_t)ml * 512 + c8) = hv;
}

// ---------------- QKV GEMM: 256x256 tile, BK=64, 8-phase counted-vmcnt schedule
// A = xh[M][512], B = Wh[1536][512] (both row-major along K). C = A·B^T + biasT.
// LDS (128 KiB): A-halves [tb*2+h] @ (tb*2+h)*8192, B-halves @ 32768 + (tb*2+h)*8192
// k-chunk XOR-swizzle (chunk ^= row&7) applied on global SOURCE + on LDS READ.
__global__ void __launch_bounds__(512, 2) qkv_gemm8_k(
        const f16* __restrict__ xh, const f16* __restrict__ Wh,
        const float* __restrict__ biasT, f16* __restrict__ qkv, int nblk) {
    extern __shared__ f16 lds[];
    int tid = threadIdx.x;
    int lane = tid & 63, wid = tid >> 6;
    int l15 = lane & 15, g = lane >> 4;
    int wm = wid >> 2, wn = wid & 3;            // 2M x 4N waves, wave tile 128x64
    int sid = (blockIdx.x & 7) * (nblk >> 3) + (blockIdx.x >> 3);
    int bm = sid / 6, bn = sid % 6;
    const f16* Ap = xh + (size_t)bm * 256 * 512;
    const f16* Bp = Wh + (size_t)bn * 256 * 512;

    // staging element offsets (2 loads/thread per half-tile), source pre-swizzled
    int li0 = tid, li1 = tid + 512;
    int r0 = li0 >> 3, c0 = li0 & 7, r1 = li1 >> 3, c1 = li1 & 7;
    int off0 = r0 * 512 + ((c0 ^ (r0 & 7)) * 8);
    int off1 = r1 * 512 + ((c1 ^ (r1 & 7)) * 8);

    auto stage = [&](const f16* panel, int ldsbase, int tt, int h) {
        int tb = tt & 1;
        int dst = ldsbase + (tb * 2 + h) * 8192 + wid * 512;   // wave-uniform
        const f16* src = panel + h * 65536 + tt * 64;
        gload_lds16(src + off0, (void*)&lds[dst]);
        gload_lds16(src + off1, (void*)&lds[dst + 4096]);
    };

    f32x4 acc[8][4];
    f32x4 zero4 = {0.f, 0.f, 0.f, 0.f};
    #pragma unroll
    for (int a = 0; a < 8; ++a)
        #pragma unroll
        for (int b = 0; b < 4; ++b) acc[a][b] = zero4;
    f16x8 bf[4][2];

    // prologue: tiles 0 and 1 fully staged
    stage(Ap, 0, 0, 0); stage(Ap, 0, 0, 1);
    stage(Bp, 32768, 0, 0); stage(Bp, 32768, 0, 1);
    stage(Ap, 0, 1, 0); stage(Ap, 0, 1, 1);
    stage(Bp, 32768, 1, 0); stage(Bp, 32768, 1, 1);
    asm volatile("s_waitcnt vmcnt(0)" ::: "memory");
    __builtin_amdgcn_s_barrier();

    #pragma unroll
    for (int tt = 0; tt < 8; ++tt) {
        int tb = tt & 1;
        const f16* Ab = &lds[(tb * 2 + wm) * 8192];
        const f16* Bb = &lds[32768 + (tb * 2 + (wn >> 1)) * 8192];
        #pragma unroll
        for (int q = 0; q < 4; ++q) {
            // ds-read this phase's A sub-tile (2 Mfrags x 2 ks)
            f16x8 af[2][2];
            #pragma unroll
            for (int ml = 0; ml < 2; ++ml) {
                int rr = (q * 2 + ml) * 16 + l15;
                #pragma unroll
                for (int ks = 0; ks < 2; ++ks)
                    af[ml][ks] = *(const f16x8*)&Ab[rr * 64 + (((ks * 4 + g) ^ (rr & 7)) * 8)];
            }
            if (q == 0) {   // all B frags for this tile (kept in regs across phases)
                #pragma unroll
                for (int nf = 0; nf < 4; ++nf) {
                    int rb = (wn & 1) * 64 + nf * 16 + l15;
                    #pragma unroll
                    for (int ks = 0; ks < 2; ++ks)
                        bf[nf][ks] = *(const f16x8*)&Bb[rb * 64 + (((ks * 4 + g) ^ (rb & 7)) * 8)];
                }
            }
            // stage one half-tile (liveness: A slots free from q0 of following tile,
            // B slots free after q0 of owning tile)
            if (q <= 1) {
                if ((tt & 1) ? (tt + 1 < 8) : (tt >= 2)) stage(Ap, 0, tt + 1, q);
            } else {
                if (tt + 2 < 8) stage(Bp, 32768, tt + 2, q - 2);
            }
            __builtin_amdgcn_s_barrier();
            __builtin_amdgcn_s_setprio(1);
            #pragma unroll
            for (int ml = 0; ml < 2; ++ml)
                #pragma unroll
                for (int nf = 0; nf < 4; ++nf)
                    #pragma unroll
                    for (int ks = 0; ks < 2; ++ks)
                        acc[q * 2 + ml][nf] = __builtin_amdgcn_mfma_f32_16x16x32_f16(
                            af[ml][ks], bf[nf][ks], acc[q * 2 + ml][nf], 0, 0, 0);
            __builtin_amdgcn_s_setprio(0);
            if (q == 3) {
                if (tt < 6)       asm volatile("s_waitcnt vmcnt(4)" ::: "memory");
                else if (tt == 6) asm volatile("s_waitcnt vmcnt(0)" ::: "memory");
            }
            __builtin_amdgcn_s_barrier();
        }
    }

    // epilogue: bias + f16 store
    int browg = bm * 256 + wm * 128, bcolg = bn * 256 + wn * 64;
    #pragma unroll
    for (int mf = 0; mf < 8; ++mf) {
        #pragma unroll
        for (int nf = 0; nf < 4; ++nf) {
            int col = bcolg + nf * 16 + l15;
            #pragma unroll
            for (int j = 0; j < 4; ++j) {
                int row = browg + mf * 16 + g * 4 + j;
                float v = acc[mf][nf][j] + biasT[(row & 63) * 1536 + col];
                qkv[(size_t)row * 1536 + col] = (f16)v;
            }
        }
    }
}

// ---------------- fused attention + output projection ----------------
__global__ __launch_bounds__(512) void attn_out_k(
        const f16* __restrict__ qkv, const f16* __restrict__ Woh,
        const float* __restrict__ b_out, float* __restrict__ out, int w0) {
    __shared__ __align__(16) char S[64 * 1024];
    int tid = threadIdx.x;
    int lane = tid & 63, h = tid >> 6;   // wave = head
    int l15 = lane & 15, g = lane >> 4;
    const f16* base = qkv + (size_t)blockIdx.x * 64 * 1536;
    int qc = h * 64, kc = 512 + h * 64, vc = 1024 + h * 64;

    f32x4 zero4 = {0.f, 0.f, 0.f, 0.f};
    f32x4 acc[4][4];
    #pragma unroll
    for (int a = 0; a < 4; ++a)
        #pragma unroll
        for (int b = 0; b < 4; ++b) acc[a][b] = zero4;

    {   // scores = q @ k^T
        f16x8 qf[4][2], kf[4][2];
        #pragma unroll
        for (int mf = 0; mf < 4; ++mf)
            #pragma unroll
            for (int ks = 0; ks < 2; ++ks)
                qf[mf][ks] = *reinterpret_cast<const f16x8*>(base + (size_t)(mf * 16 + l15) * 1536 + qc + ks * 32 + g * 8);
        #pragma unroll
        for (int nf = 0; nf < 4; ++nf)
            #pragma unroll
            for (int ks = 0; ks < 2; ++ks)
                kf[nf][ks] = *reinterpret_cast<const f16x8*>(base + (size_t)(nf * 16 + l15) * 1536 + kc + ks * 32 + g * 8);
        #pragma unroll
        for (int ks = 0; ks < 2; ++ks)
            #pragma unroll
            for (int mf = 0; mf < 4; ++mf)
                #pragma unroll
                for (int nf = 0; nf < 4; ++nf)
                    acc[mf][nf] = __builtin_amdgcn_mfma_f32_16x16x32_f16(qf[mf][ks], kf[nf][ks], acc[mf][nf], 0, 0, 0);
    }

    // V fragments (B-operand): strided f16 gathers, L2/L3-hot
    f16x8 vf[4][2];
    #pragma unroll
    for (int nf = 0; nf < 4; ++nf)
        #pragma unroll
        for (int ks = 0; ks < 2; ++ks) {
            f16x8 v;
            #pragma unroll
            for (int j = 0; j < 8; ++j)
                v[j] = base[(size_t)(ks * 32 + g * 8 + j) * 1536 + vc + nf * 16 + l15];
            vf[nf][ks] = v;
        }

    // softmax over keys; P -> swizzled LDS at cols [h*64, h*64+64)
    #pragma unroll
    for (int mf = 0; mf < 4; ++mf) {
        #pragma unroll
        for (int j = 0; j < 4; ++j) {
            float mx = -1e30f;
            #pragma unroll
            for (int nf = 0; nf < 4; ++nf) mx = fmaxf(mx, acc[mf][nf][j]);
            #pragma unroll
            for (int off = 1; off < 16; off <<= 1) mx = fmaxf(mx, __shfl_xor(mx, off));
            float e[4], sum = 0.f;
            #pragma unroll
            for (int nf = 0; nf < 4; ++nf) {
                e[nf] = __expf((acc[mf][nf][j] - mx) * 0.125f);
                sum += e[nf];
            }
            #pragma unroll
            for (int off = 1; off < 16; off <<= 1) sum += __shfl_xor(sum, off);
            float rinv = __fdividef(1.0f, sum);
            int row = mf * 16 + g * 4 + j;
            #pragma unroll
            for (int nf = 0; nf < 4; ++nf)
                *sp(S, row, h * 64 + nf * 16 + l15) = (f16)(e[nf] * rinv);
        }
    }

    // out_h = P @ V  (own LDS slice; no barrier needed)
    f32x4 acc2[4][4];
    #pragma unroll
    for (int a = 0; a < 4; ++a)
        #pragma unroll
        for (int b = 0; b < 4; ++b) acc2[a][b] = zero4;
    #pragma unroll
    for (int ks = 0; ks < 2; ++ks)
        #pragma unroll
        for (int mf = 0; mf < 4; ++mf) {
            f16x8 pa = *reinterpret_cast<const f16x8*>(sp(S, mf * 16 + l15, h * 64 + ks * 32 + g * 8));
            #pragma unroll
            for (int nf = 0; nf < 4; ++nf)
                acc2[mf][nf] = __builtin_amdgcn_mfma_f32_16x16x32_f16(pa, vf[nf][ks], acc2[mf][nf], 0, 0, 0);
        }
    #pragma unroll
    for (int mf = 0; mf < 4; ++mf)
        #pragma unroll
        for (int nf = 0; nf < 4; ++nf)
            #pragma unroll
            for (int j = 0; j < 4; ++j)
                *sp(S, mf * 16 + g * 4 + j, h * 64 + nf * 16 + l15) = (f16)acc2[mf][nf][j];

    __syncthreads();

    // output projection: wave h computes cols [h*64, h*64+64), K = 512 from LDS
    int ocol0 = h * 64;
    float bo[4];
    #pragma unroll
    for (int nf = 0; nf < 4; ++nf) bo[nf] = b_out[ocol0 + nf * 16 + l15];

    #pragma unroll
    for (int a = 0; a < 4; ++a)
        #pragma unroll
        for (int b = 0; b < 4; ++b) acc[a][b] = zero4;
    for (int ks = 0; ks < 16; ++ks) {
        f16x8 af[4], bf[4];
        #pragma unroll
        for (int mf = 0; mf < 4; ++mf)
            af[mf] = *reinterpret_cast<const f16x8*>(sp(S, mf * 16 + l15, ks * 32 + g * 8));
        #pragma unroll
        for (int nf = 0; nf < 4; ++nf)
            bf[nf] = *reinterpret_cast<const f16x8*>(Woh + (size_t)(ocol0 + nf * 16 + l15) * 512 + ks * 32 + g * 8);
        #pragma unroll
        for (int mf = 0; mf < 4; ++mf)
            #pragma unroll
            for (int nf = 0; nf < 4; ++nf)
                acc[mf][nf] = __builtin_amdgcn_mfma_f32_16x16x32_f16(af[mf], bf[nf], acc[mf][nf], 0, 0, 0);
    }

    int wglob = w0 + blockIdx.x;
    #pragma unroll
    for (int mf = 0; mf < 4; ++mf) {
        #pragma unroll
        for (int j = 0; j < 4; ++j) {
            int srow = src_row(wglob * 64 + mf * 16 + g * 4 + j);
            #pragma unroll
            for (int nf = 0; nf < 4; ++nf)
                out[(size_t)srow * 512 + ocol0 + nf * 16 + l15] = acc[mf][nf][j] + bo[nf];
        }
    }
}

extern "C" void kernel_launch(void* const* d_in, const int* in_sizes, int n_in,
                              void* d_out, int out_size, void* d_ws, size_t ws_size,
                              hipStream_t stream) {
    (void)in_sizes; (void)n_in; (void)out_size;
    const float* x     = (const float*)d_in[0];
    const float* pos   = (const float*)d_in[1];
    const float* W_in  = (const float*)d_in[2];
    const float* b_in  = (const float*)d_in[3];
    const float* W_out = (const float*)d_in[4];
    const float* b_out = (const float*)d_in[5];
    float* out = (float*)d_out;

    char* ws = (char*)d_ws;
    f16*   Wi_h  = (f16*)ws;                  // 1,572,864 B
    f16*   Wo_h  = (f16*)(ws + 1572864);      //   524,288 B
    float* biasT = (float*)(ws + 2097152);    //   393,216 B
    const size_t fixed = 2490368;

    // chunk so xh+qkv stay L3-resident and fit ws (4096 B per row)
    int chunks = 4;
    while (chunks < 64) {
        size_t need = fixed + ((size_t)131072 / chunks) * 4096;
        if (need <= ws_size) break;
        chunks <<= 1;
    }
    int Mc = 131072 / chunks;
    f16* xh  = (f16*)(ws + fixed);
    f16* qkv = (f16*)(ws + fixed + (size_t)Mc * 1024);
    int nblk = (Mc / 256) * 6;

    static_cast<void>(hipFuncSetAttribute((const void*)qkv_gemm8_k,
        hipFuncAttributeMaxDynamicSharedMemorySize, 131072));

    prep_weights_k<<<1024, 256, 0, stream>>>(W_in, W_out, Wi_h, Wo_h);
    prep_bias_k<<<384, 256, 0, stream>>>(pos, W_in, b_in, biasT);
    for (int c = 0; c < chunks; ++c) {
        int m0 = c * Mc;
        prep_x_k<<<Mc / 4, 256, 0, stream>>>(x, xh, m0);
        qkv_gemm8_k<<<nblk, 512, 131072, stream>>>(xh, Wi_h, biasT, qkv, nblk);
        attn_out_k<<<Mc / 64, 512, 0, stream>>>(qkv, Wo_h, b_out, out, c * (Mc / 64));
    }
}

// Round 4
// 634.964 us; speedup vs baseline: 1.4234x; 1.0237x over previous
//
#include <hip/hip_runtime.h>

typedef _Float16 f16;
typedef unsigned int u32;
typedef f16 f16x8 __attribute__((ext_vector_type(8)));
typedef f16 f16x4 __attribute__((ext_vector_type(4)));
typedef float f32x4 __attribute__((ext_vector_type(4)));

// N=4,T=8,H=64,W=64,C=512, WS=8, heads=8, head_dim=64
// windows = 2048, tokens/window = 64, M = 131072, K = 512, Nqkv = 1536

__device__ __forceinline__ int src_row(int m) {
    int win = m >> 6, s = m & 63;
    return ((win >> 6) << 12) | (((win >> 3) & 7) << 9) | ((s >> 3) << 6) |
           ((win & 7) << 3) | (s & 7);
}

__device__ __forceinline__ void gload_lds16(const void* g, void* lds) {
    __builtin_amdgcn_global_load_lds(
        (const __attribute__((address_space(1))) u32*)g,
        (__attribute__((address_space(3))) u32*)lds, 16, 0, 0);
}

// swizzled LDS accessor for attn kernel: rows x 512 f16, XOR bits 4-6
__device__ __forceinline__ f16* sp(char* S, int r, int c) {
    return (f16*)(S + r * 1024 + ((c * 2) ^ ((r & 7) << 4)));
}

// ---------------- prep: weights fp32 -> fp16 ----------------
__global__ __launch_bounds__(256) void prep_weights_k(
        const float* __restrict__ Wi, const float* __restrict__ Wo,
        f16* __restrict__ Wi_h, f16* __restrict__ Wo_h) {
    int i = blockIdx.x * 256 + threadIdx.x;    // 262144 float4s total
    const float4* src;
    f16* dst;
    int idx;
    if (i < 196608) { src = (const float4*)Wi; dst = Wi_h; idx = i; }
    else            { src = (const float4*)Wo; dst = Wo_h; idx = i - 196608; }
    float4 v = src[idx];
    f16x4 h = {(f16)v.x, (f16)v.y, (f16)v.z, (f16)v.w};
    *(f16x4*)(dst + (size_t)idx * 4) = h;
}

// ---------------- prep: biasT[s][o] = b_in[o] + (o<1024 ? pos[s]·W_in[o] : 0)
__global__ __launch_bounds__(256) void prep_bias_k(
        const float* __restrict__ pos, const float* __restrict__ Wi,
        const float* __restrict__ b_in, float* __restrict__ biasT) {
    int idx = blockIdx.x * 256 + threadIdx.x;   // 64*1536
    int s = idx / 1536, o = idx % 1536;
    float acc = b_in[o];
    if (o < 1024) {
        const float4* p4 = (const float4*)(pos + (size_t)s * 512);
        const float4* w4 = (const float4*)(Wi + (size_t)o * 512);
        #pragma unroll 4
        for (int c = 0; c < 128; ++c) {
            float4 a = p4[c], b = w4[c];
            acc += a.x * b.x + a.y * b.y + a.z * b.z + a.w * b.w;
        }
    }
    biasT[idx] = acc;
}

// ---------------- prep: x fp32 -> window-major f16 chunk ----------------
__global__ __launch_bounds__(256) void prep_x_k(
        const float* __restrict__ x, f16* __restrict__ xh, int m0) {
    int i = blockIdx.x * 256 + threadIdx.x;    // Mc*64
    int ml = i >> 6, c8 = (i & 63) * 8;
    int sr = src_row(m0 + ml);
    const float4* s4 = (const float4*)(x + (size_t)sr * 512 + c8);
    float4 a = s4[0], b = s4[1];
    f16x8 hv = {(f16)a.x, (f16)a.y, (f16)a.z, (f16)a.w,
                (f16)b.x, (f16)b.y, (f16)b.z, (f16)b.w};
    *(f16x8*)(xh + (size_t)ml * 512 + c8) = hv;
}

// ---------------- QKV GEMM: 256x256 tile, BK=64, 8-phase counted-vmcnt ----------------
__global__ void __launch_bounds__(512, 2) qkv_gemm8_k(
        const f16* __restrict__ xh, const f16* __restrict__ Wh,
        const float* __restrict__ biasT, f16* __restrict__ qkv, int nblk) {
    extern __shared__ f16 lds[];
    int tid = threadIdx.x;
    int lane = tid & 63, wid = tid >> 6;
    int l15 = lane & 15, g = lane >> 4;
    int wm = wid >> 2, wn = wid & 3;            // 2M x 4N waves, wave tile 128x64
    int sid = (blockIdx.x & 7) * (nblk >> 3) + (blockIdx.x >> 3);
    int bm = sid / 6, bn = sid % 6;
    const f16* Ap = xh + (size_t)bm * 256 * 512;
    const f16* Bp = Wh + (size_t)bn * 256 * 512;

    int li0 = tid, li1 = tid + 512;
    int r0 = li0 >> 3, c0 = li0 & 7, r1 = li1 >> 3, c1 = li1 & 7;
    int off0 = r0 * 512 + ((c0 ^ (r0 & 7)) * 8);
    int off1 = r1 * 512 + ((c1 ^ (r1 & 7)) * 8);

    auto stage = [&](const f16* panel, int ldsbase, int tt, int h) {
        int tb = tt & 1;
        int dst = ldsbase + (tb * 2 + h) * 8192 + wid * 512;   // wave-uniform
        const f16* src = panel + h * 65536 + tt * 64;
        gload_lds16(src + off0, (void*)&lds[dst]);
        gload_lds16(src + off1, (void*)&lds[dst + 4096]);
    };

    f32x4 acc[8][4];
    f32x4 zero4 = {0.f, 0.f, 0.f, 0.f};
    #pragma unroll
    for (int a = 0; a < 8; ++a)
        #pragma unroll
        for (int b = 0; b < 4; ++b) acc[a][b] = zero4;
    f16x8 bf[4][2];

    stage(Ap, 0, 0, 0); stage(Ap, 0, 0, 1);
    stage(Bp, 32768, 0, 0); stage(Bp, 32768, 0, 1);
    stage(Ap, 0, 1, 0); stage(Ap, 0, 1, 1);
    stage(Bp, 32768, 1, 0); stage(Bp, 32768, 1, 1);
    asm volatile("s_waitcnt vmcnt(0)" ::: "memory");
    __builtin_amdgcn_s_barrier();

    #pragma unroll
    for (int tt = 0; tt < 8; ++tt) {
        int tb = tt & 1;
        const f16* Ab = &lds[(tb * 2 + wm) * 8192];
        const f16* Bb = &lds[32768 + (tb * 2 + (wn >> 1)) * 8192];
        #pragma unroll
        for (int q = 0; q < 4; ++q) {
            f16x8 af[2][2];
            #pragma unroll
            for (int ml = 0; ml < 2; ++ml) {
                int rr = (q * 2 + ml) * 16 + l15;
                #pragma unroll
                for (int ks = 0; ks < 2; ++ks)
                    af[ml][ks] = *(const f16x8*)&Ab[rr * 64 + (((ks * 4 + g) ^ (rr & 7)) * 8)];
            }
            if (q == 0) {
                #pragma unroll
                for (int nf = 0; nf < 4; ++nf) {
                    int rb = (wn & 1) * 64 + nf * 16 + l15;
                    #pragma unroll
                    for (int ks = 0; ks < 2; ++ks)
                        bf[nf][ks] = *(const f16x8*)&Bb[rb * 64 + (((ks * 4 + g) ^ (rb & 7)) * 8)];
                }
            }
            if (q <= 1) {
                if ((tt & 1) ? (tt + 1 < 8) : (tt >= 2)) stage(Ap, 0, tt + 1, q);
            } else {
                if (tt + 2 < 8) stage(Bp, 32768, tt + 2, q - 2);
            }
            __builtin_amdgcn_s_barrier();
            __builtin_amdgcn_s_setprio(1);
            #pragma unroll
            for (int ml = 0; ml < 2; ++ml)
                #pragma unroll
                for (int nf = 0; nf < 4; ++nf)
                    #pragma unroll
                    for (int ks = 0; ks < 2; ++ks)
                        acc[q * 2 + ml][nf] = __builtin_amdgcn_mfma_f32_16x16x32_f16(
                            af[ml][ks], bf[nf][ks], acc[q * 2 + ml][nf], 0, 0, 0);
            __builtin_amdgcn_s_setprio(0);
            if (q == 3) {
                if (tt < 6)       asm volatile("s_waitcnt vmcnt(4)" ::: "memory");
                else if (tt == 6) asm volatile("s_waitcnt vmcnt(0)" ::: "memory");
            }
            __builtin_amdgcn_s_barrier();
        }
    }

    int browg = bm * 256 + wm * 128, bcolg = bn * 256 + wn * 64;
    #pragma unroll
    for (int mf = 0; mf < 8; ++mf) {
        #pragma unroll
        for (int nf = 0; nf < 4; ++nf) {
            int col = bcolg + nf * 16 + l15;
            #pragma unroll
            for (int j = 0; j < 4; ++j) {
                int row = browg + mf * 16 + g * 4 + j;
                float v = acc[mf][nf][j] + biasT[(row & 63) * 1536 + col];
                qkv[(size_t)row * 1536 + col] = (f16)v;
            }
        }
    }
}

// ---------------- attention (QK^T, softmax, PV) -> attn_h f16 ----------------
__global__ __launch_bounds__(512) void attn_k(
        const f16* __restrict__ qkv, f16* __restrict__ attn_h) {
    __shared__ __align__(16) char S[64 * 1024];   // 8 heads x (64x64 f16, swizzled rows)
    int tid = threadIdx.x;
    int lane = tid & 63, h = tid >> 6;   // wave = head
    int l15 = lane & 15, g = lane >> 4;
    const f16* base = qkv + (size_t)blockIdx.x * 64 * 1536;
    int qc = h * 64, kc = 512 + h * 64, vc = 1024 + h * 64;

    f32x4 zero4 = {0.f, 0.f, 0.f, 0.f};
    f32x4 acc[4][4];
    #pragma unroll
    for (int a = 0; a < 4; ++a)
        #pragma unroll
        for (int b = 0; b < 4; ++b) acc[a][b] = zero4;

    {   // scores = q @ k^T
        f16x8 qf[4][2], kf[4][2];
        #pragma unroll
        for (int mf = 0; mf < 4; ++mf)
            #pragma unroll
            for (int ks = 0; ks < 2; ++ks)
                qf[mf][ks] = *reinterpret_cast<const f16x8*>(base + (size_t)(mf * 16 + l15) * 1536 + qc + ks * 32 + g * 8);
        #pragma unroll
        for (int nf = 0; nf < 4; ++nf)
            #pragma unroll
            for (int ks = 0; ks < 2; ++ks)
                kf[nf][ks] = *reinterpret_cast<const f16x8*>(base + (size_t)(nf * 16 + l15) * 1536 + kc + ks * 32 + g * 8);
        #pragma unroll
        for (int ks = 0; ks < 2; ++ks)
            #pragma unroll
            for (int mf = 0; mf < 4; ++mf)
                #pragma unroll
                for (int nf = 0; nf < 4; ++nf)
                    acc[mf][nf] = __builtin_amdgcn_mfma_f32_16x16x32_f16(qf[mf][ks], kf[nf][ks], acc[mf][nf], 0, 0, 0);
    }

    // V fragments (B-operand): strided f16 gathers, cache-hot
    f16x8 vf[4][2];
    #pragma unroll
    for (int nf = 0; nf < 4; ++nf)
        #pragma unroll
        for (int ks = 0; ks < 2; ++ks) {
            f16x8 v;
            #pragma unroll
            for (int j = 0; j < 8; ++j)
                v[j] = base[(size_t)(ks * 32 + g * 8 + j) * 1536 + vc + nf * 16 + l15];
            vf[nf][ks] = v;
        }

    // softmax; P -> this head's LDS slice (rows swizzled)
    char* Sh = S + h * 8192;
    #pragma unroll
    for (int mf = 0; mf < 4; ++mf) {
        #pragma unroll
        for (int j = 0; j < 4; ++j) {
            float mx = -1e30f;
            #pragma unroll
            for (int nf = 0; nf < 4; ++nf) mx = fmaxf(mx, acc[mf][nf][j]);
            #pragma unroll
            for (int off = 1; off < 16; off <<= 1) mx = fmaxf(mx, __shfl_xor(mx, off));
            float e[4], sum = 0.f;
            #pragma unroll
            for (int nf = 0; nf < 4; ++nf) {
                e[nf] = __expf((acc[mf][nf][j] - mx) * 0.125f);
                sum += e[nf];
            }
            #pragma unroll
            for (int off = 1; off < 16; off <<= 1) sum += __shfl_xor(sum, off);
            float rinv = __fdividef(1.0f, sum);
            int row = mf * 16 + g * 4 + j;
            #pragma unroll
            for (int nf = 0; nf < 4; ++nf)
                *(f16*)(Sh + row * 128 + (((nf * 16 + l15) * 2) ^ ((row & 7) << 4))) = (f16)(e[nf] * rinv);
        }
    }

    // out_h = P @ V  (own slice; wave-local, no barrier)
    f32x4 acc2[4][4];
    #pragma unroll
    for (int a = 0; a < 4; ++a)
        #pragma unroll
        for (int b = 0; b < 4; ++b) acc2[a][b] = zero4;
    #pragma unroll
    for (int ks = 0; ks < 2; ++ks)
        #pragma unroll
        for (int mf = 0; mf < 4; ++mf) {
            int rr = mf * 16 + l15;
            f16x8 pa = *reinterpret_cast<const f16x8*>(Sh + rr * 128 + (((ks * 32 + g * 8) * 2) ^ ((rr & 7) << 4)));
            #pragma unroll
            for (int nf = 0; nf < 4; ++nf)
                acc2[mf][nf] = __builtin_amdgcn_mfma_f32_16x16x32_f16(pa, vf[nf][ks], acc2[mf][nf], 0, 0, 0);
        }

    f16* dst = attn_h + (size_t)blockIdx.x * 64 * 512 + h * 64;
    #pragma unroll
    for (int mf = 0; mf < 4; ++mf)
        #pragma unroll
        for (int nf = 0; nf < 4; ++nf)
            #pragma unroll
            for (int j = 0; j < 4; ++j)
                dst[(size_t)(mf * 16 + g * 4 + j) * 512 + nf * 16 + l15] = (f16)acc2[mf][nf][j];
}

// ---------------- output projection: 8-phase 256x256 GEMM + scatter ----------------
__global__ void __launch_bounds__(512, 2) proj_gemm8_k(
        const f16* __restrict__ attn_h, const f16* __restrict__ Woh,
        const float* __restrict__ b_out, float* __restrict__ out, int nblk, int m0) {
    extern __shared__ f16 lds[];
    int tid = threadIdx.x;
    int lane = tid & 63, wid = tid >> 6;
    int l15 = lane & 15, g = lane >> 4;
    int wm = wid >> 2, wn = wid & 3;
    int sid = (blockIdx.x & 7) * (nblk >> 3) + (blockIdx.x >> 3);
    int bm = sid >> 1, bn = sid & 1;
    const f16* Ap = attn_h + (size_t)bm * 256 * 512;
    const f16* Bp = Woh + (size_t)bn * 256 * 512;

    int li0 = tid, li1 = tid + 512;
    int r0 = li0 >> 3, c0 = li0 & 7, r1 = li1 >> 3, c1 = li1 & 7;
    int off0 = r0 * 512 + ((c0 ^ (r0 & 7)) * 8);
    int off1 = r1 * 512 + ((c1 ^ (r1 & 7)) * 8);

    auto stage = [&](const f16* panel, int ldsbase, int tt, int h) {
        int tb = tt & 1;
        int dst = ldsbase + (tb * 2 + h) * 8192 + wid * 512;
        const f16* src = panel + h * 65536 + tt * 64;
        gload_lds16(src + off0, (void*)&lds[dst]);
        gload_lds16(src + off1, (void*)&lds[dst + 4096]);
    };

    f32x4 acc[8][4];
    f32x4 zero4 = {0.f, 0.f, 0.f, 0.f};
    #pragma unroll
    for (int a = 0; a < 8; ++a)
        #pragma unroll
        for (int b = 0; b < 4; ++b) acc[a][b] = zero4;
    f16x8 bf[4][2];

    stage(Ap, 0, 0, 0); stage(Ap, 0, 0, 1);
    stage(Bp, 32768, 0, 0); stage(Bp, 32768, 0, 1);
    stage(Ap, 0, 1, 0); stage(Ap, 0, 1, 1);
    stage(Bp, 32768, 1, 0); stage(Bp, 32768, 1, 1);
    asm volatile("s_waitcnt vmcnt(0)" ::: "memory");
    __builtin_amdgcn_s_barrier();

    #pragma unroll
    for (int tt = 0; tt < 8; ++tt) {
        int tb = tt & 1;
        const f16* Ab = &lds[(tb * 2 + wm) * 8192];
        const f16* Bb = &lds[32768 + (tb * 2 + (wn >> 1)) * 8192];
        #pragma unroll
        for (int q = 0; q < 4; ++q) {
            f16x8 af[2][2];
            #pragma unroll
            for (int ml = 0; ml < 2; ++ml) {
                int rr = (q * 2 + ml) * 16 + l15;
                #pragma unroll
                for (int ks = 0; ks < 2; ++ks)
                    af[ml][ks] = *(const f16x8*)&Ab[rr * 64 + (((ks * 4 + g) ^ (rr & 7)) * 8)];
            }
            if (q == 0) {
                #pragma unroll
                for (int nf = 0; nf < 4; ++nf) {
                    int rb = (wn & 1) * 64 + nf * 16 + l15;
                    #pragma unroll
                    for (int ks = 0; ks < 2; ++ks)
                        bf[nf][ks] = *(const f16x8*)&Bb[rb * 64 + (((ks * 4 + g) ^ (rb & 7)) * 8)];
                }
            }
            if (q <= 1) {
                if ((tt & 1) ? (tt + 1 < 8) : (tt >= 2)) stage(Ap, 0, tt + 1, q);
            } else {
                if (tt + 2 < 8) stage(Bp, 32768, tt + 2, q - 2);
            }
            __builtin_amdgcn_s_barrier();
            __builtin_amdgcn_s_setprio(1);
            #pragma unroll
            for (int ml = 0; ml < 2; ++ml)
                #pragma unroll
                for (int nf = 0; nf < 4; ++nf)
                    #pragma unroll
                    for (int ks = 0; ks < 2; ++ks)
                        acc[q * 2 + ml][nf] = __builtin_amdgcn_mfma_f32_16x16x32_f16(
                            af[ml][ks], bf[nf][ks], acc[q * 2 + ml][nf], 0, 0, 0);
            __builtin_amdgcn_s_setprio(0);
            if (q == 3) {
                if (tt < 6)       asm volatile("s_waitcnt vmcnt(4)" ::: "memory");
                else if (tt == 6) asm volatile("s_waitcnt vmcnt(0)" ::: "memory");
            }
            __builtin_amdgcn_s_barrier();
        }
    }

    int browg = bm * 256 + wm * 128, bcolg = bn * 256 + wn * 64;
    #pragma unroll
    for (int nf = 0; nf < 4; ++nf) {
        int col = bcolg + nf * 16 + l15;
        float bo = b_out[col];
        #pragma unroll
        for (int mf = 0; mf < 8; ++mf) {
            #pragma unroll
            for (int j = 0; j < 4; ++j) {
                int srow = src_row(m0 + browg + mf * 16 + g * 4 + j);
                out[(size_t)srow * 512 + col] = acc[mf][nf][j] + bo;
            }
        }
    }
}

extern "C" void kernel_launch(void* const* d_in, const int* in_sizes, int n_in,
                              void* d_out, int out_size, void* d_ws, size_t ws_size,
                              hipStream_t stream) {
    (void)in_sizes; (void)n_in; (void)out_size;
    const float* x     = (const float*)d_in[0];
    const float* pos   = (const float*)d_in[1];
    const float* W_in  = (const float*)d_in[2];
    const float* b_in  = (const float*)d_in[3];
    const float* W_out = (const float*)d_in[4];
    const float* b_out = (const float*)d_in[5];
    float* out = (float*)d_out;

    char* ws = (char*)d_ws;
    f16*   Wi_h  = (f16*)ws;                  // 1,572,864 B
    f16*   Wo_h  = (f16*)(ws + 1572864);      //   524,288 B
    float* biasT = (float*)(ws + 2097152);    //   393,216 B
    const size_t fixed = 2490368;

    // 4096 B per row: xh/attn_h (aliased, 1024 B) + qkv (3072 B). chunks=1 = R1's proven-fit 539 MB.
    int chunks = 1;
    while (chunks < 64) {
        size_t need = fixed + ((size_t)131072 / chunks) * 4096;
        if (need <= ws_size) break;
        chunks <<= 1;
    }
    int Mc = 131072 / chunks;
    f16* xh  = (f16*)(ws + fixed);            // also attn_h (xh dead after qkv_gemm)
    f16* qkv = (f16*)(ws + fixed + (size_t)Mc * 1024);
    int nblk  = (Mc / 256) * 6;
    int nblk2 = (Mc / 256) * 2;

    static_cast<void>(hipFuncSetAttribute((const void*)qkv_gemm8_k,
        hipFuncAttributeMaxDynamicSharedMemorySize, 131072));
    static_cast<void>(hipFuncSetAttribute((const void*)proj_gemm8_k,
        hipFuncAttributeMaxDynamicSharedMemorySize, 131072));

    prep_weights_k<<<1024, 256, 0, stream>>>(W_in, W_out, Wi_h, Wo_h);
    prep_bias_k<<<384, 256, 0, stream>>>(pos, W_in, b_in, biasT);
    for (int c = 0; c < chunks; ++c) {
        int m0 = c * Mc;
        prep_x_k<<<Mc / 4, 256, 0, stream>>>(x, xh, m0);
        qkv_gemm8_k<<<nblk, 512, 131072, stream>>>(xh, Wi_h, biasT, qkv, nblk);
        attn_k<<<Mc / 64, 512, 0, stream>>>(qkv, xh);
        proj_gemm8_k<<<nblk2, 512, 131072, stream>>>(xh, Wo_h, b_out, out, nblk2, m0);
    }
}

// Round 5
// 599.933 us; speedup vs baseline: 1.5065x; 1.0584x over previous
//
#include <hip/hip_runtime.h>

typedef _Float16 f16;
typedef unsigned int u32;
typedef f16 f16x8 __attribute__((ext_vector_type(8)));
typedef f16 f16x4 __attribute__((ext_vector_type(4)));
typedef float f32x4 __attribute__((ext_vector_type(4)));

// N=4,T=8,H=64,W=64,C=512, WS=8, heads=8, head_dim=64
// windows = 2048, tokens/window = 64, M = 131072, K = 512, Nqkv = 1536

__device__ __forceinline__ int src_row(int m) {
    int win = m >> 6, s = m & 63;
    return ((win >> 6) << 12) | (((win >> 3) & 7) << 9) | ((s >> 3) << 6) |
           ((win & 7) << 3) | (s & 7);
}

__device__ __forceinline__ void gload_lds16(const void* g, void* lds) {
    __builtin_amdgcn_global_load_lds(
        (const __attribute__((address_space(1))) u32*)g,
        (__attribute__((address_space(3))) u32*)lds, 16, 0, 0);
}

// ---------------- prep: weights fp32 -> fp16 ----------------
__global__ __launch_bounds__(256) void prep_weights_k(
        const float* __restrict__ Wi, const float* __restrict__ Wo,
        f16* __restrict__ Wi_h, f16* __restrict__ Wo_h) {
    int i = blockIdx.x * 256 + threadIdx.x;    // 262144 float4s total
    const float4* src;
    f16* dst;
    int idx;
    if (i < 196608) { src = (const float4*)Wi; dst = Wi_h; idx = i; }
    else            { src = (const float4*)Wo; dst = Wo_h; idx = i - 196608; }
    float4 v = src[idx];
    f16x4 h = {(f16)v.x, (f16)v.y, (f16)v.z, (f16)v.w};
    *(f16x4*)(dst + (size_t)idx * 4) = h;
}

// ---------------- prep: biasT[s][o] = b_in[o] + (o<1024 ? pos[s]·W_in[o] : 0)
__global__ __launch_bounds__(256) void prep_bias_k(
        const float* __restrict__ pos, const float* __restrict__ Wi,
        const float* __restrict__ b_in, float* __restrict__ biasT) {
    int idx = blockIdx.x * 256 + threadIdx.x;   // 64*1536
    int s = idx / 1536, o = idx % 1536;
    float acc = b_in[o];
    if (o < 1024) {
        const float4* p4 = (const float4*)(pos + (size_t)s * 512);
        const float4* w4 = (const float4*)(Wi + (size_t)o * 512);
        #pragma unroll 4
        for (int c = 0; c < 128; ++c) {
            float4 a = p4[c], b = w4[c];
            acc += a.x * b.x + a.y * b.y + a.z * b.z + a.w * b.w;
        }
    }
    biasT[idx] = acc;
}

// ---------------- prep: x fp32 -> window-major f16 chunk ----------------
__global__ __launch_bounds__(256) void prep_x_k(
        const float* __restrict__ x, f16* __restrict__ xh, int m0) {
    int i = blockIdx.x * 256 + threadIdx.x;    // Mc*64
    int ml = i >> 6, c8 = (i & 63) * 8;
    int sr = src_row(m0 + ml);
    const float4* s4 = (const float4*)(x + (size_t)sr * 512 + c8);
    float4 a = s4[0], b = s4[1];
    f16x8 hv = {(f16)a.x, (f16)a.y, (f16)a.z, (f16)a.w,
                (f16)b.x, (f16)b.y, (f16)b.z, (f16)b.w};
    *(f16x8*)(xh + (size_t)ml * 512 + c8) = hv;
}

// ---------------- QKV GEMM: 256x256 tile, BK=64, 8-phase counted-vmcnt ----------------
// Q,K cols (bn<4) -> qk[row][0..1023]; V cols (bn>=4) -> vT[win][head][d][s] via LDS transpose
__global__ void __launch_bounds__(512, 2) qkv_gemm8_k(
        const f16* __restrict__ xh, const f16* __restrict__ Wh,
        const float* __restrict__ biasT, f16* __restrict__ qk,
        f16* __restrict__ vT, int nblk) {
    extern __shared__ f16 lds[];
    int tid = threadIdx.x;
    int lane = tid & 63, wid = tid >> 6;
    int l15 = lane & 15, g = lane >> 4;
    int wm = wid >> 2, wn = wid & 3;            // 2M x 4N waves, wave tile 128x64
    int sid = (blockIdx.x & 7) * (nblk >> 3) + (blockIdx.x >> 3);
    int bm = sid / 6, bn = sid % 6;
    const f16* Ap = xh + (size_t)bm * 256 * 512;
    const f16* Bp = Wh + (size_t)bn * 256 * 512;

    int li0 = tid, li1 = tid + 512;
    int r0 = li0 >> 3, c0 = li0 & 7, r1 = li1 >> 3, c1 = li1 & 7;
    int off0 = r0 * 512 + ((c0 ^ (r0 & 7)) * 8);
    int off1 = r1 * 512 + ((c1 ^ (r1 & 7)) * 8);

    auto stage = [&](const f16* panel, int ldsbase, int tt, int h) {
        int tb = tt & 1;
        int dst = ldsbase + (tb * 2 + h) * 8192 + wid * 512;   // wave-uniform
        const f16* src = panel + h * 65536 + tt * 64;
        gload_lds16(src + off0, (void*)&lds[dst]);
        gload_lds16(src + off1, (void*)&lds[dst + 4096]);
    };

    f32x4 acc[8][4];
    f32x4 zero4 = {0.f, 0.f, 0.f, 0.f};
    #pragma unroll
    for (int a = 0; a < 8; ++a)
        #pragma unroll
        for (int b = 0; b < 4; ++b) acc[a][b] = zero4;
    f16x8 bf[4][2];

    stage(Ap, 0, 0, 0); stage(Ap, 0, 0, 1);
    stage(Bp, 32768, 0, 0); stage(Bp, 32768, 0, 1);
    stage(Ap, 0, 1, 0); stage(Ap, 0, 1, 1);
    stage(Bp, 32768, 1, 0); stage(Bp, 32768, 1, 1);
    asm volatile("s_waitcnt vmcnt(0)" ::: "memory");
    __builtin_amdgcn_s_barrier();

    #pragma unroll
    for (int tt = 0; tt < 8; ++tt) {
        int tb = tt & 1;
        const f16* Ab = &lds[(tb * 2 + wm) * 8192];
        const f16* Bb = &lds[32768 + (tb * 2 + (wn >> 1)) * 8192];
        #pragma unroll
        for (int q = 0; q < 4; ++q) {
            f16x8 af[2][2];
            #pragma unroll
            for (int ml = 0; ml < 2; ++ml) {
                int rr = (q * 2 + ml) * 16 + l15;
                #pragma unroll
                for (int ks = 0; ks < 2; ++ks)
                    af[ml][ks] = *(const f16x8*)&Ab[rr * 64 + (((ks * 4 + g) ^ (rr & 7)) * 8)];
            }
            if (q == 0) {
                #pragma unroll
                for (int nf = 0; nf < 4; ++nf) {
                    int rb = (wn & 1) * 64 + nf * 16 + l15;
                    #pragma unroll
                    for (int ks = 0; ks < 2; ++ks)
                        bf[nf][ks] = *(const f16x8*)&Bb[rb * 64 + (((ks * 4 + g) ^ (rb & 7)) * 8)];
                }
            }
            if (q <= 1) {
                if ((tt & 1) ? (tt + 1 < 8) : (tt >= 2)) stage(Ap, 0, tt + 1, q);
            } else {
                if (tt + 2 < 8) stage(Bp, 32768, tt + 2, q - 2);
            }
            __builtin_amdgcn_s_barrier();
            __builtin_amdgcn_s_setprio(1);
            #pragma unroll
            for (int ml = 0; ml < 2; ++ml)
                #pragma unroll
                for (int nf = 0; nf < 4; ++nf)
                    #pragma unroll
                    for (int ks = 0; ks < 2; ++ks)
                        acc[q * 2 + ml][nf] = __builtin_amdgcn_mfma_f32_16x16x32_f16(
                            af[ml][ks], bf[nf][ks], acc[q * 2 + ml][nf], 0, 0, 0);
            __builtin_amdgcn_s_setprio(0);
            if (q == 3) {
                if (tt < 6)       asm volatile("s_waitcnt vmcnt(4)" ::: "memory");
                else if (tt == 6) asm volatile("s_waitcnt vmcnt(0)" ::: "memory");
            }
            __builtin_amdgcn_s_barrier();
        }
    }

    int browg = bm * 256 + wm * 128;
    if (bn < 4) {
        // Q,K: bias (row-dependent) + f16 store, row stride 1024
        #pragma unroll
        for (int mf = 0; mf < 8; ++mf) {
            #pragma unroll
            for (int nf = 0; nf < 4; ++nf) {
                int col = bn * 256 + wn * 64 + nf * 16 + l15;
                #pragma unroll
                for (int j = 0; j < 4; ++j) {
                    int row = browg + mf * 16 + g * 4 + j;
                    float v = acc[mf][nf][j] + biasT[(row & 63) * 1536 + col];
                    qk[(size_t)row * 1024 + col] = (f16)v;
                }
            }
        }
    } else {
        // V: bias is row-independent (pos only touches cols<1024). Transpose via LDS.
        __syncthreads();
        char* T = (char*)lds;   // 256 d-rows x 512 B, XOR-swizzled
        int bn2 = bn - 4;
        #pragma unroll
        for (int mf = 0; mf < 8; ++mf) {
            #pragma unroll
            for (int nf = 0; nf < 4; ++nf) {
                int dl = wn * 64 + nf * 16 + l15;           // 0..255
                float bo = biasT[1024 + bn2 * 256 + dl];    // s=0 row of table
                #pragma unroll
                for (int j = 0; j < 4; ++j) {
                    int sl = wm * 128 + mf * 16 + g * 4 + j;  // 0..255
                    *(f16*)(T + dl * 512 + ((sl * 2) ^ ((dl & 7) << 4))) =
                        (f16)(acc[mf][nf][j] + bo);
                }
            }
        }
        __syncthreads();
        // coalesced read-back + store: vT[win][head][d][s]
        #pragma unroll
        for (int r = 0; r < 16; ++r) {
            int c = r * 512 + tid;              // 0..8191 chunks of 16B
            int dl = c >> 5, s0 = (c & 31) * 8;
            f16x8 v = *(const f16x8*)(T + dl * 512 + ((s0 * 2) ^ ((dl & 7) << 4)));
            int gcol = bn2 * 256 + dl;          // 0..511
            int head = gcol >> 6, dd = gcol & 63;
            int win = bm * 4 + (s0 >> 6);
            *(f16x8*)(vT + (size_t)win * 32768 + head * 4096 + dd * 64 + (s0 & 63)) = v;
        }
    }
}

// ---------------- attention (QK^T, softmax, PV) -> attn_h f16 ----------------
__global__ __launch_bounds__(512) void attn_k(
        const f16* __restrict__ qk, const f16* __restrict__ vT,
        f16* __restrict__ attn_h) {
    __shared__ __align__(16) char S[64 * 1024];   // 8 heads x 8 KB P-slices
    int tid = threadIdx.x;
    int lane = tid & 63, h = tid >> 6;   // wave = head
    int l15 = lane & 15, g = lane >> 4;
    const f16* baseqk = qk + (size_t)blockIdx.x * 64 * 1024;
    const f16* basev  = vT + (size_t)blockIdx.x * 32768 + h * 4096;
    int qc = h * 64, kc = 512 + h * 64;

    f32x4 zero4 = {0.f, 0.f, 0.f, 0.f};
    f32x4 acc[4][4];
    #pragma unroll
    for (int a = 0; a < 4; ++a)
        #pragma unroll
        for (int b = 0; b < 4; ++b) acc[a][b] = zero4;

    {   // scores = q @ k^T
        f16x8 qf[4][2], kf[4][2];
        #pragma unroll
        for (int mf = 0; mf < 4; ++mf)
            #pragma unroll
            for (int ks = 0; ks < 2; ++ks)
                qf[mf][ks] = *reinterpret_cast<const f16x8*>(baseqk + (size_t)(mf * 16 + l15) * 1024 + qc + ks * 32 + g * 8);
        #pragma unroll
        for (int nf = 0; nf < 4; ++nf)
            #pragma unroll
            for (int ks = 0; ks < 2; ++ks)
                kf[nf][ks] = *reinterpret_cast<const f16x8*>(baseqk + (size_t)(nf * 16 + l15) * 1024 + kc + ks * 32 + g * 8);
        #pragma unroll
        for (int ks = 0; ks < 2; ++ks)
            #pragma unroll
            for (int mf = 0; mf < 4; ++mf)
                #pragma unroll
                for (int nf = 0; nf < 4; ++nf)
                    acc[mf][nf] = __builtin_amdgcn_mfma_f32_16x16x32_f16(qf[mf][ks], kf[nf][ks], acc[mf][nf], 0, 0, 0);
    }

    // V fragments: contiguous f16x8 reads from vT rows (B-frag: lane holds V[s][d=l15])
    f16x8 vf[4][2];
    #pragma unroll
    for (int nf = 0; nf < 4; ++nf)
        #pragma unroll
        for (int ks = 0; ks < 2; ++ks)
            vf[nf][ks] = *reinterpret_cast<const f16x8*>(basev + (nf * 16 + l15) * 64 + ks * 32 + g * 8);

    // softmax; P -> this head's LDS slice (rows swizzled)
    char* Sh = S + h * 8192;
    #pragma unroll
    for (int mf = 0; mf < 4; ++mf) {
        #pragma unroll
        for (int j = 0; j < 4; ++j) {
            float mx = -1e30f;
            #pragma unroll
            for (int nf = 0; nf < 4; ++nf) mx = fmaxf(mx, acc[mf][nf][j]);
            #pragma unroll
            for (int off = 1; off < 16; off <<= 1) mx = fmaxf(mx, __shfl_xor(mx, off));
            float e[4], sum = 0.f;
            #pragma unroll
            for (int nf = 0; nf < 4; ++nf) {
                e[nf] = __expf((acc[mf][nf][j] - mx) * 0.125f);
                sum += e[nf];
            }
            #pragma unroll
            for (int off = 1; off < 16; off <<= 1) sum += __shfl_xor(sum, off);
            float rinv = __fdividef(1.0f, sum);
            int row = mf * 16 + g * 4 + j;
            #pragma unroll
            for (int nf = 0; nf < 4; ++nf)
                *(f16*)(Sh + row * 128 + (((nf * 16 + l15) * 2) ^ ((row & 7) << 4))) = (f16)(e[nf] * rinv);
        }
    }

    // out_h = P @ V  (own slice; wave-local, no barrier)
    f32x4 acc2[4][4];
    #pragma unroll
    for (int a = 0; a < 4; ++a)
        #pragma unroll
        for (int b = 0; b < 4; ++b) acc2[a][b] = zero4;
    #pragma unroll
    for (int ks = 0; ks < 2; ++ks)
        #pragma unroll
        for (int mf = 0; mf < 4; ++mf) {
            int rr = mf * 16 + l15;
            f16x8 pa = *reinterpret_cast<const f16x8*>(Sh + rr * 128 + (((ks * 32 + g * 8) * 2) ^ ((rr & 7) << 4)));
            #pragma unroll
            for (int nf = 0; nf < 4; ++nf)
                acc2[mf][nf] = __builtin_amdgcn_mfma_f32_16x16x32_f16(pa, vf[nf][ks], acc2[mf][nf], 0, 0, 0);
        }

    f16* dst = attn_h + (size_t)blockIdx.x * 64 * 512 + h * 64;
    #pragma unroll
    for (int mf = 0; mf < 4; ++mf)
        #pragma unroll
        for (int nf = 0; nf < 4; ++nf)
            #pragma unroll
            for (int j = 0; j < 4; ++j)
                dst[(size_t)(mf * 16 + g * 4 + j) * 512 + nf * 16 + l15] = (f16)acc2[mf][nf][j];
}

// ---------------- output projection: 8-phase 256x256 GEMM + scatter ----------------
__global__ void __launch_bounds__(512, 2) proj_gemm8_k(
        const f16* __restrict__ attn_h, const f16* __restrict__ Woh,
        const float* __restrict__ b_out, float* __restrict__ out, int nblk, int m0) {
    extern __shared__ f16 lds[];
    int tid = threadIdx.x;
    int lane = tid & 63, wid = tid >> 6;
    int l15 = lane & 15, g = lane >> 4;
    int wm = wid >> 2, wn = wid & 3;
    int sid = (blockIdx.x & 7) * (nblk >> 3) + (blockIdx.x >> 3);
    int bm = sid >> 1, bn = sid & 1;
    const f16* Ap = attn_h + (size_t)bm * 256 * 512;
    const f16* Bp = Woh + (size_t)bn * 256 * 512;

    int li0 = tid, li1 = tid + 512;
    int r0 = li0 >> 3, c0 = li0 & 7, r1 = li1 >> 3, c1 = li1 & 7;
    int off0 = r0 * 512 + ((c0 ^ (r0 & 7)) * 8);
    int off1 = r1 * 512 + ((c1 ^ (r1 & 7)) * 8);

    auto stage = [&](const f16* panel, int ldsbase, int tt, int h) {
        int tb = tt & 1;
        int dst = ldsbase + (tb * 2 + h) * 8192 + wid * 512;
        const f16* src = panel + h * 65536 + tt * 64;
        gload_lds16(src + off0, (void*)&lds[dst]);
        gload_lds16(src + off1, (void*)&lds[dst + 4096]);
    };

    f32x4 acc[8][4];
    f32x4 zero4 = {0.f, 0.f, 0.f, 0.f};
    #pragma unroll
    for (int a = 0; a < 8; ++a)
        #pragma unroll
        for (int b = 0; b < 4; ++b) acc[a][b] = zero4;
    f16x8 bf[4][2];

    stage(Ap, 0, 0, 0); stage(Ap, 0, 0, 1);
    stage(Bp, 32768, 0, 0); stage(Bp, 32768, 0, 1);
    stage(Ap, 0, 1, 0); stage(Ap, 0, 1, 1);
    stage(Bp, 32768, 1, 0); stage(Bp, 32768, 1, 1);
    asm volatile("s_waitcnt vmcnt(0)" ::: "memory");
    __builtin_amdgcn_s_barrier();

    #pragma unroll
    for (int tt = 0; tt < 8; ++tt) {
        int tb = tt & 1;
        const f16* Ab = &lds[(tb * 2 + wm) * 8192];
        const f16* Bb = &lds[32768 + (tb * 2 + (wn >> 1)) * 8192];
        #pragma unroll
        for (int q = 0; q < 4; ++q) {
            f16x8 af[2][2];
            #pragma unroll
            for (int ml = 0; ml < 2; ++ml) {
                int rr = (q * 2 + ml) * 16 + l15;
                #pragma unroll
                for (int ks = 0; ks < 2; ++ks)
                    af[ml][ks] = *(const f16x8*)&Ab[rr * 64 + (((ks * 4 + g) ^ (rr & 7)) * 8)];
            }
            if (q == 0) {
                #pragma unroll
                for (int nf = 0; nf < 4; ++nf) {
                    int rb = (wn & 1) * 64 + nf * 16 + l15;
                    #pragma unroll
                    for (int ks = 0; ks < 2; ++ks)
                        bf[nf][ks] = *(const f16x8*)&Bb[rb * 64 + (((ks * 4 + g) ^ (rb & 7)) * 8)];
                }
            }
            if (q <= 1) {
                if ((tt & 1) ? (tt + 1 < 8) : (tt >= 2)) stage(Ap, 0, tt + 1, q);
            } else {
                if (tt + 2 < 8) stage(Bp, 32768, tt + 2, q - 2);
            }
            __builtin_amdgcn_s_barrier();
            __builtin_amdgcn_s_setprio(1);
            #pragma unroll
            for (int ml = 0; ml < 2; ++ml)
                #pragma unroll
                for (int nf = 0; nf < 4; ++nf)
                    #pragma unroll
                    for (int ks = 0; ks < 2; ++ks)
                        acc[q * 2 + ml][nf] = __builtin_amdgcn_mfma_f32_16x16x32_f16(
                            af[ml][ks], bf[nf][ks], acc[q * 2 + ml][nf], 0, 0, 0);
            __builtin_amdgcn_s_setprio(0);
            if (q == 3) {
                if (tt < 6)       asm volatile("s_waitcnt vmcnt(4)" ::: "memory");
                else if (tt == 6) asm volatile("s_waitcnt vmcnt(0)" ::: "memory");
            }
            __builtin_amdgcn_s_barrier();
        }
    }

    int browg = bm * 256 + wm * 128, bcolg = bn * 256 + wn * 64;
    #pragma unroll
    for (int nf = 0; nf < 4; ++nf) {
        int col = bcolg + nf * 16 + l15;
        float bo = b_out[col];
        #pragma unroll
        for (int mf = 0; mf < 8; ++mf) {
            #pragma unroll
            for (int j = 0; j < 4; ++j) {
                int srow = src_row(m0 + browg + mf * 16 + g * 4 + j);
                out[(size_t)srow * 512 + col] = acc[mf][nf][j] + bo;
            }
        }
    }
}

extern "C" void kernel_launch(void* const* d_in, const int* in_sizes, int n_in,
                              void* d_out, int out_size, void* d_ws, size_t ws_size,
                              hipStream_t stream) {
    (void)in_sizes; (void)n_in; (void)out_size;
    const float* x     = (const float*)d_in[0];
    const float* pos   = (const float*)d_in[1];
    const float* W_in  = (const float*)d_in[2];
    const float* b_in  = (const float*)d_in[3];
    const float* W_out = (const float*)d_in[4];
    const float* b_out = (const float*)d_in[5];
    float* out = (float*)d_out;

    char* ws = (char*)d_ws;
    f16*   Wi_h  = (f16*)ws;                  // 1,572,864 B
    f16*   Wo_h  = (f16*)(ws + 1572864);      //   524,288 B
    float* biasT = (float*)(ws + 2097152);    //   393,216 B
    const size_t fixed = 2490368;

    // 4096 B per row: xh/attn_h (1024, aliased) + qk (2048) + vT (1024).
    // chunks=4 keeps the ~130 MB working set L3-resident.
    int chunks = 4;
    while (chunks < 64) {
        size_t need = fixed + ((size_t)131072 / chunks) * 4096;
        if (need <= ws_size) break;
        chunks <<= 1;
    }
    int Mc = 131072 / chunks;
    f16* xh = (f16*)(ws + fixed);             // also attn_h (xh dead after qkv_gemm)
    f16* qk = (f16*)(ws + fixed + (size_t)Mc * 1024);
    f16* vT = (f16*)(ws + fixed + (size_t)Mc * 3072);
    int nblk  = (Mc / 256) * 6;
    int nblk2 = (Mc / 256) * 2;

    static_cast<void>(hipFuncSetAttribute((const void*)qkv_gemm8_k,
        hipFuncAttributeMaxDynamicSharedMemorySize, 131072));
    static_cast<void>(hipFuncSetAttribute((const void*)proj_gemm8_k,
        hipFuncAttributeMaxDynamicSharedMemorySize, 131072));

    prep_weights_k<<<1024, 256, 0, stream>>>(W_in, W_out, Wi_h, Wo_h);
    prep_bias_k<<<384, 256, 0, stream>>>(pos, W_in, b_in, biasT);
    for (int c = 0; c < chunks; ++c) {
        int m0 = c * Mc;
        prep_x_k<<<Mc / 4, 256, 0, stream>>>(x, xh, m0);
        qkv_gemm8_k<<<nblk, 512, 131072, stream>>>(xh, Wi_h, biasT, qk, vT, nblk);
        attn_k<<<Mc / 64, 512, 0, stream>>>(qk, vT, xh);
        proj_gemm8_k<<<nblk2, 512, 131072, stream>>>(xh, Wo_h, b_out, out, nblk2, m0);
    }
}